// Round 10
// baseline (150.214 us; speedup 1.0000x reference)
//
#include <hip/hip_runtime.h>
#include <hip/hip_cooperative_groups.h>

namespace cg = cooperative_groups;

#define Hdim   128
#define Anodes 512
#define Bbatch 64
#define Eedges 16384
#define AMASK  (Anodes - 1)

// ws float offsets
#define WS_W1T  0        // bf16[128][128] stored as 8192 floats
#define WS_U    8192     // f32[512][128]
#define WS_CARR 73728    // f32[512] per-node C contribution
#define WS_PB   74240    // f32[64] per-batch partials

typedef __attribute__((ext_vector_type(8))) short short8;
typedef __attribute__((ext_vector_type(4))) float f32x4;

__device__ __forceinline__ short f2bf(float f) {
    union { float f; unsigned u; } v; v.f = f;
    unsigned r = v.u + 0x7FFFu + ((v.u >> 16) & 1u);
    return (short)(r >> 16);
}

// Single cooperative kernel, 512 blocks x 256 threads (2 blocks/CU via 77KB LDS).
// Phase 1 (block s): per-source aggregation -> U[s,:], CARR[s];
//   blocks 0..3 also transpose w1 strip -> bf16 w1T; block 4 zeroes WS_PB.
// grid.sync
// Phase 2 (block = 8 chunks x 64 batches): MFMA relu(x@w1+b1).U partials -> WS_PB.
// grid.sync
// Phase 3: block 0 publishes out.
__global__ __launch_bounds__(256)
void k_all(const float* __restrict__ x, const int* __restrict__ ei,
           const float* __restrict__ w1, const float* __restrict__ b1,
           const float* __restrict__ w2, const float* __restrict__ b2,
           const float* __restrict__ wfc, const float* __restrict__ bfc,
           float* __restrict__ ws, float* __restrict__ out) {
    cg::grid_group grid = cg::this_grid();

    __shared__ float w2L[Hdim][Hdim + 1];   // 66 KB; reused as transpose tile / w1s
    __shared__ unsigned short dl[1024];
    __shared__ unsigned flag[Anodes];
    __shared__ unsigned cntL[Anodes];
    __shared__ float plist[1024];
    __shared__ float Gr[Hdim];
    __shared__ float gred[Hdim];
    __shared__ float red[4];
    __shared__ int nz;
    __shared__ int sawS;

    const int tid = threadIdx.x;
    const int s = blockIdx.x;

    // ---------------- Phase 1 ----------------
    if (s < 4) {   // w1T strip transpose (uses w2L as tile), then falls through
        const int k0 = s * 32;
        for (int i = tid; i < 32 * 128; i += 256) {
            int r = i >> 7, c = i & 127;
            w2L[r][c] = w1[(k0 + r) * Hdim + c];
        }
        __syncthreads();
        short* o = (short*)(ws + WS_W1T);
        const int n = tid >> 1, j0 = (tid & 1) * 16;
        short tmp[16];
        #pragma unroll
        for (int j = 0; j < 16; ++j) tmp[j] = f2bf(w2L[j0 + j][n]);
        short8* dst = (short8*)(o + n * Hdim + k0 + j0);
        dst[0] = *(short8*)(tmp);
        dst[1] = *(short8*)(tmp + 8);
        __syncthreads();
    }
    if (s == 4 && tid < Bbatch) ws[WS_PB + tid] = 0.f;

    for (int i = tid; i < Anodes; i += 256) { flag[i] = 0u; cntL[i] = 0u; }
    if (tid == 0) { nz = 0; sawS = 0; }
    __syncthreads();

    // stage w2 (independent of scans)
    for (int i = tid; i < Hdim * Hdim; i += 256)
        w2L[i >> 7][i & 127] = w2[i];

    const int4* s4 = (const int4*)ei;
    const int4* d4 = (const int4*)(ei + Eedges);
    // scan 1: collect dst's of edges with src==s
    for (int i = tid; i < Eedges / 4; i += 256) {
        int4 sv = s4[i];
        int4 dv = d4[i];
        int d;
        if ((sv.x & AMASK) == s) { d = dv.x & AMASK; dl[atomicAdd(&nz, 1)] = (unsigned short)d; flag[d] = 1u; }
        if ((sv.y & AMASK) == s) { d = dv.y & AMASK; dl[atomicAdd(&nz, 1)] = (unsigned short)d; flag[d] = 1u; }
        if ((sv.z & AMASK) == s) { d = dv.z & AMASK; dl[atomicAdd(&nz, 1)] = (unsigned short)d; flag[d] = 1u; }
        if ((sv.w & AMASK) == s) { d = dv.w & AMASK; dl[atomicAdd(&nz, 1)] = (unsigned short)d; flag[d] = 1u; }
    }
    __syncthreads();
    // scan 2: count flagged dst's; detect s as dst
    for (int i = tid; i < Eedges / 4; i += 256) {
        int4 dv = d4[i];
        int d;
        d = dv.x & AMASK; if (flag[d]) atomicAdd(&cntL[d], 1u); if (d == s) sawS = 1;
        d = dv.y & AMASK; if (flag[d]) atomicAdd(&cntL[d], 1u); if (d == s) sawS = 1;
        d = dv.z & AMASK; if (flag[d]) atomicAdd(&cntL[d], 1u); if (d == s) sawS = 1;
        d = dv.w & AMASK; if (flag[d]) atomicAdd(&cntL[d], 1u); if (d == s) sawS = 1;
    }
    __syncthreads();
    const int nzn = nz;
    for (int i = tid; i < nzn; i += 256)
        plist[i] = 1.0f / fmaxf((float)cntL[dl[i]], 1.0f);
    __syncthreads();

    {
        const int k = tid & 127, half = tid >> 7;
        float g = 0.f;
        for (int i = half; i < nzn; i += 2)
            g += plist[i] * wfc[(size_t)dl[i] * Hdim + k];
        if (half) gred[k] = g;
        __syncthreads();
        if (!half) Gr[k] = g + gred[k];
        __syncthreads();

        // U[s,k] = sum_h w2[k,h] * Gr[h]  (f32 exact)
        float u = 0.f;
        const int h0 = half * 64;
        #pragma unroll 8
        for (int hh = h0; hh < h0 + 64; ++hh) u += w2L[k][hh] * Gr[hh];
        if (half) gred[k] = u;
        __syncthreads();
        if (!half) ws[WS_U + (size_t)s * Hdim + k] = u + gred[k];

        // c[s] = sawS ? b2 . wfc[s,:] : 0
        float cv = 0.f;
        if (tid < 128) cv = b2[tid] * wfc[(size_t)s * Hdim + tid];
        #pragma unroll
        for (int off = 32; off; off >>= 1) cv += __shfl_down(cv, off, 64);
        __syncthreads();
        if (tid == 0)  gred[0] = cv;
        if (tid == 64) gred[1] = cv;
        __syncthreads();
        if (tid == 0) ws[WS_CARR + s] = sawS ? (gred[0] + gred[1]) : 0.f;
    }

    grid.sync();

    // ---------------- Phase 2: MFMA main ----------------
    {
        short* w1s = (short*)&w2L[0][0];   // 32 KB alias
        const short8* gsrc = (const short8*)(ws + WS_W1T);
        for (int i = tid; i < 2048; i += 256) {
            short8 v = gsrc[i];
            int n = i >> 4;
            int byte = (i * 16) ^ ((n & 7) << 4);
            *(short8*)((char*)w1s + byte) = v;
        }
        __syncthreads();

        const int row0 = s * 64;
        const int b    = s >> 3;
        const int a0   = (s & 7) * 64;
        const int w = tid >> 6;
        const int l = tid & 63;
        const int c = l & 15;
        const int g = l >> 4;

        const float* xrow = x + (size_t)(row0 + w * 16 + c) * Hdim;

        f32x4 acc[8];
        #pragma unroll
        for (int n = 0; n < 8; ++n) acc[n] = (f32x4){0.f, 0.f, 0.f, 0.f};

        #pragma unroll
        for (int ks = 0; ks < 4; ++ks) {
            const int k0 = ks * 32;
            float4 a_lo = *(const float4*)(xrow + k0 + 8 * g);
            float4 a_hi = *(const float4*)(xrow + k0 + 8 * g + 4);
            short8 a;
            a[0] = f2bf(a_lo.x); a[1] = f2bf(a_lo.y); a[2] = f2bf(a_lo.z); a[3] = f2bf(a_lo.w);
            a[4] = f2bf(a_hi.x); a[5] = f2bf(a_hi.y); a[6] = f2bf(a_hi.z); a[7] = f2bf(a_hi.w);
            #pragma unroll
            for (int n = 0; n < 8; ++n) {
                int byte = (((n * 16 + c) << 8) + ((k0 + 8 * g) << 1)) ^ ((c & 7) << 4);
                short8 bf = *(short8*)((char*)w1s + byte);
                acc[n] = __builtin_amdgcn_mfma_f32_16x16x32_bf16(a, bf, acc[n], 0, 0, 0);
            }
        }

        float part = 0.f;
        const float* U = ws + WS_U;
        #pragma unroll
        for (int n = 0; n < 8; ++n) {
            const int colg = n * 16 + c;
            const float bv = b1[colg];
            #pragma unroll
            for (int r = 0; r < 4; ++r) {
                const int arow = a0 + w * 16 + g * 4 + r;
                float z = acc[n][r] + bv;
                part += fmaxf(z, 0.f) * U[arow * Hdim + colg];
            }
        }
        #pragma unroll
        for (int off = 32; off; off >>= 1) part += __shfl_down(part, off, 64);
        if (l == 0) red[w] = part;
        __syncthreads();

        // fold per-chunk C contribution (+bfc once per b)
        float cw = 0.f;
        if (tid < 64) cw = ws[WS_CARR + a0 + tid];
        #pragma unroll
        for (int off = 32; off; off >>= 1) cw += __shfl_down(cw, off, 64);
        if (tid == 0) {
            float v = red[0] + red[1] + red[2] + red[3] + cw;
            if (a0 == 0) v += bfc[0];
            atomicAdd(ws + WS_PB + b, v);
        }
    }

    grid.sync();

    // ---------------- Phase 3: publish ----------------
    if (s == 0 && tid < Bbatch)
        out[tid] = atomicAdd(ws + WS_PB + tid, 0.0f);   // coherent read
}

extern "C" void kernel_launch(void* const* d_in, const int* in_sizes, int n_in,
                              void* d_out, int out_size, void* d_ws, size_t ws_size,
                              hipStream_t stream) {
    const float* x   = (const float*)d_in[0];
    // d_in[1] = pos (unused)
    const int*   ei  = (const int*)d_in[2];
    const float* w1  = (const float*)d_in[3];
    const float* b1  = (const float*)d_in[4];
    const float* w2  = (const float*)d_in[5];
    const float* b2  = (const float*)d_in[6];
    const float* wfc = (const float*)d_in[7];
    const float* bfc = (const float*)d_in[8];
    float* out = (float*)d_out;
    float* ws  = (float*)d_ws;

    void* args[] = { (void*)&x, (void*)&ei, (void*)&w1, (void*)&b1, (void*)&w2,
                     (void*)&b2, (void*)&wfc, (void*)&bfc, (void*)&ws, (void*)&out };
    hipLaunchCooperativeKernel((const void*)k_all, dim3(512), dim3(256),
                               args, 0, stream);
}

// Round 11
// 38.235 us; speedup vs baseline: 3.9287x; 3.9287x over previous
//
#include <hip/hip_runtime.h>

#define Hdim   128
#define Anodes 512
#define Bbatch 64
#define Eedges 16384
#define AMASK  (Anodes - 1)

// ws float offsets
#define WS_W1T  0        // bf16[128][128] stored as 8192 floats
#define WS_U    8192     // f32[512][128]
#define WS_CARR 73728    // f32[512] per-node C contribution
#define WS_PB   74240    // f32[64] per-batch partials (zeroed in k_G)
#define WS_CTR  74304    // u32[64] per-batch arrival counters (zeroed in k_G)

typedef __attribute__((ext_vector_type(8))) short short8;
typedef __attribute__((ext_vector_type(4))) float f32x4;

__device__ __forceinline__ short f2bf(float f) {
    union { float f; unsigned u; } v; v.f = f;
    unsigned r = v.u + 0x7FFFu + ((v.u >> 16) & 1u);
    return (short)(r >> 16);
}

// n1: blocks 0..511 (s): per-source aggregation -> U[s,:], CARR[s]
//     blocks 512..515: w1 -> bf16 w1T strip transpose
//     block 516: zero WS_PB + WS_CTR
__global__ __launch_bounds__(256)
void k_G(const int* __restrict__ ei, const float* __restrict__ w1,
         const float* __restrict__ w2, const float* __restrict__ wfc,
         const float* __restrict__ b2, float* __restrict__ ws) {
    __shared__ float w2L[Hdim][Hdim + 1];   // 66 KB (also transpose tile)
    __shared__ unsigned short dl[1024];
    __shared__ unsigned flag[Anodes];
    __shared__ unsigned cntL[Anodes];
    __shared__ float plist[1024];
    __shared__ float Gr[Hdim];
    __shared__ float gred[Hdim];
    __shared__ int nz;
    __shared__ int sawS;

    const int tid = threadIdx.x;
    const int s = blockIdx.x;

    if (s >= Anodes) {
        if (s < Anodes + 4) {                // w1T strips
            const int k0 = (s - Anodes) * 32;
            for (int i = tid; i < 32 * 128; i += 256) {
                int r = i >> 7, c = i & 127;
                w2L[r][c] = w1[(k0 + r) * Hdim + c];
            }
            __syncthreads();
            short* o = (short*)(ws + WS_W1T);
            const int n = tid >> 1, j0 = (tid & 1) * 16;
            short tmp[16];
            #pragma unroll
            for (int j = 0; j < 16; ++j) tmp[j] = f2bf(w2L[j0 + j][n]);
            short8* dst = (short8*)(o + n * Hdim + k0 + j0);
            dst[0] = *(short8*)(tmp);
            dst[1] = *(short8*)(tmp + 8);
        } else {                             // zero partials + counters
            if (tid < Bbatch) ws[WS_PB + tid] = 0.f;
            if (tid >= 64 && tid < 64 + Bbatch) ((unsigned*)(ws + WS_CTR))[tid - 64] = 0u;
        }
        return;
    }

    for (int i = tid; i < Anodes; i += 256) { flag[i] = 0u; cntL[i] = 0u; }
    if (tid == 0) { nz = 0; sawS = 0; }
    __syncthreads();

    // stage w2 (no dependency on scans)
    for (int i = tid; i < Hdim * Hdim; i += 256)
        w2L[i >> 7][i & 127] = w2[i];

    const int4* s4 = (const int4*)ei;
    const int4* d4 = (const int4*)(ei + Eedges);
    // scan 1: collect dst's of edges with src==s
    for (int i = tid; i < Eedges / 4; i += 256) {
        int4 sv = s4[i];
        int4 dv = d4[i];
        int d;
        if ((sv.x & AMASK) == s) { d = dv.x & AMASK; dl[atomicAdd(&nz, 1)] = (unsigned short)d; flag[d] = 1u; }
        if ((sv.y & AMASK) == s) { d = dv.y & AMASK; dl[atomicAdd(&nz, 1)] = (unsigned short)d; flag[d] = 1u; }
        if ((sv.z & AMASK) == s) { d = dv.z & AMASK; dl[atomicAdd(&nz, 1)] = (unsigned short)d; flag[d] = 1u; }
        if ((sv.w & AMASK) == s) { d = dv.w & AMASK; dl[atomicAdd(&nz, 1)] = (unsigned short)d; flag[d] = 1u; }
    }
    __syncthreads();
    // scan 2: count flagged dst's; detect s as dst
    for (int i = tid; i < Eedges / 4; i += 256) {
        int4 dv = d4[i];
        int d;
        d = dv.x & AMASK; if (flag[d]) atomicAdd(&cntL[d], 1u); if (d == s) sawS = 1;
        d = dv.y & AMASK; if (flag[d]) atomicAdd(&cntL[d], 1u); if (d == s) sawS = 1;
        d = dv.z & AMASK; if (flag[d]) atomicAdd(&cntL[d], 1u); if (d == s) sawS = 1;
        d = dv.w & AMASK; if (flag[d]) atomicAdd(&cntL[d], 1u); if (d == s) sawS = 1;
    }
    __syncthreads();
    const int n = nz;
    for (int i = tid; i < n; i += 256)
        plist[i] = 1.0f / fmaxf((float)cntL[dl[i]], 1.0f);
    __syncthreads();

    const int k = tid & 127, half = tid >> 7;
    float g = 0.f;
    for (int i = half; i < n; i += 2)
        g += plist[i] * wfc[(size_t)dl[i] * Hdim + k];
    if (half) gred[k] = g;
    __syncthreads();
    if (!half) Gr[k] = g + gred[k];
    __syncthreads();

    // U[s,k] = sum_h w2[k,h] * Gr[h]  (f32 exact)
    float u = 0.f;
    const int h0 = half * 64;
    #pragma unroll 8
    for (int hh = h0; hh < h0 + 64; ++hh) u += w2L[k][hh] * Gr[hh];
    if (half) gred[k] = u;
    __syncthreads();
    if (!half) ws[WS_U + (size_t)s * Hdim + k] = u + gred[k];

    // c[s] = sawS ? b2 . wfc[s,:] : 0
    float cv = 0.f;
    if (tid < 128) cv = b2[tid] * wfc[(size_t)s * Hdim + tid];
    #pragma unroll
    for (int off = 32; off; off >>= 1) cv += __shfl_down(cv, off, 64);
    __syncthreads();            // gred free for reuse
    if (tid == 0)  gred[0] = cv;
    if (tid == 64) gred[1] = cv;
    __syncthreads();
    if (tid == 0) ws[WS_CARR + s] = sawS ? (gred[0] + gred[1]) : 0.f;
}

// n2: MFMA; block (b, chunk): partial -> atomicAdd ws[WS_PB+b];
//     8th arriving block per b publishes out[b] (device-scope coherent).
__global__ __launch_bounds__(256)
void k_main(const float* __restrict__ x, const float* __restrict__ b1,
            const float* __restrict__ bfc, float* __restrict__ ws,
            float* __restrict__ out) {
    __shared__ short w1s[Hdim * Hdim];   // swizzled bf16 [n][k], 32 KB
    __shared__ float red[4];

    const int tid  = threadIdx.x;
    const int row0 = blockIdx.x * 64;
    const int b    = blockIdx.x >> 3;
    const int a0   = (blockIdx.x & 7) * 64;

    {
        const short8* gsrc = (const short8*)(ws + WS_W1T);
        for (int i = tid; i < 2048; i += 256) {
            short8 v = gsrc[i];
            int n = i >> 4;
            int byte = (i * 16) ^ ((n & 7) << 4);
            *(short8*)((char*)w1s + byte) = v;
        }
    }
    __syncthreads();

    const int w = tid >> 6;
    const int l = tid & 63;
    const int c = l & 15;
    const int g = l >> 4;

    const float* xrow = x + (size_t)(row0 + w * 16 + c) * Hdim;

    f32x4 acc[8];
    #pragma unroll
    for (int n = 0; n < 8; ++n) acc[n] = (f32x4){0.f, 0.f, 0.f, 0.f};

    #pragma unroll
    for (int ks = 0; ks < 4; ++ks) {
        const int k0 = ks * 32;
        float4 a_lo = *(const float4*)(xrow + k0 + 8 * g);
        float4 a_hi = *(const float4*)(xrow + k0 + 8 * g + 4);
        short8 a;
        a[0] = f2bf(a_lo.x); a[1] = f2bf(a_lo.y); a[2] = f2bf(a_lo.z); a[3] = f2bf(a_lo.w);
        a[4] = f2bf(a_hi.x); a[5] = f2bf(a_hi.y); a[6] = f2bf(a_hi.z); a[7] = f2bf(a_hi.w);
        #pragma unroll
        for (int n = 0; n < 8; ++n) {
            int byte = (((n * 16 + c) << 8) + ((k0 + 8 * g) << 1)) ^ ((c & 7) << 4);
            short8 bf = *(short8*)((char*)w1s + byte);
            acc[n] = __builtin_amdgcn_mfma_f32_16x16x32_bf16(a, bf, acc[n], 0, 0, 0);
        }
    }

    float part = 0.f;
    const float* U = ws + WS_U;
    #pragma unroll
    for (int n = 0; n < 8; ++n) {
        const int colg = n * 16 + c;
        const float bv = b1[colg];
        #pragma unroll
        for (int r = 0; r < 4; ++r) {
            const int arow = a0 + w * 16 + g * 4 + r;
            float z = acc[n][r] + bv;
            part += fmaxf(z, 0.f) * U[arow * Hdim + colg];
        }
    }
    #pragma unroll
    for (int off = 32; off; off >>= 1) part += __shfl_down(part, off, 64);
    if (l == 0) red[w] = part;
    __syncthreads();

    // fold per-chunk C contribution (+bfc once per b)
    float cw = 0.f;
    if (tid < 64) cw = ws[WS_CARR + a0 + tid];
    #pragma unroll
    for (int off = 32; off; off >>= 1) cw += __shfl_down(cw, off, 64);
    if (tid == 0) {
        float v = red[0] + red[1] + red[2] + red[3] + cw;
        if (a0 == 0) v += bfc[0];
        atomicAdd(ws + WS_PB + b, v);
        __threadfence();                                   // order add before arrival
        unsigned* ctr = (unsigned*)(ws + WS_CTR);
        unsigned old = atomicAdd(&ctr[b], 1u);
        if (old == 7u) {                                   // last arrival publishes
            out[b] = atomicAdd(ws + WS_PB + b, 0.0f);      // coherent read
        }
    }
}

extern "C" void kernel_launch(void* const* d_in, const int* in_sizes, int n_in,
                              void* d_out, int out_size, void* d_ws, size_t ws_size,
                              hipStream_t stream) {
    const float* x   = (const float*)d_in[0];
    // d_in[1] = pos (unused)
    const int*   ei  = (const int*)d_in[2];
    const float* w1  = (const float*)d_in[3];
    const float* b1  = (const float*)d_in[4];
    const float* w2  = (const float*)d_in[5];
    const float* b2  = (const float*)d_in[6];
    const float* wfc = (const float*)d_in[7];
    const float* bfc = (const float*)d_in[8];
    float* out = (float*)d_out;
    float* ws  = (float*)d_ws;

    hipLaunchKernelGGL(k_G,    dim3(517), dim3(256), 0, stream, ei, w1, w2, wfc, b2, ws);
    hipLaunchKernelGGL(k_main, dim3(512), dim3(256), 0, stream, x, b1, bfc, ws, out);
}

// Round 12
// 33.189 us; speedup vs baseline: 4.5260x; 1.1520x over previous
//
#include <hip/hip_runtime.h>

#define Hdim   128
#define Anodes 512
#define Bbatch 64
#define Eedges 16384
#define AMASK  (Anodes - 1)

// ws float offsets
#define WS_W1T  0        // bf16[128][128] stored as 8192 floats
#define WS_U    8192     // f32[512][128]
#define WS_CARR 73728    // f32[512] per-node C contribution

typedef __attribute__((ext_vector_type(8))) short short8;
typedef __attribute__((ext_vector_type(4))) float f32x4;

__device__ __forceinline__ short f2bf(float f) {
    union { float f; unsigned u; } v; v.f = f;
    unsigned r = v.u + 0x7FFFu + ((v.u >> 16) & 1u);
    return (short)(r >> 16);
}

// n1: blocks 0..511 (s): per-source aggregation -> U[s,:], CARR[s]
//     blocks 512..515: w1 -> bf16 w1T strip transpose
//     block 516: out[b] = bfc (poison-overwrite + bias init)
__global__ __launch_bounds__(256)
void k_G(const int* __restrict__ ei, const float* __restrict__ w1,
         const float* __restrict__ w2, const float* __restrict__ wfc,
         const float* __restrict__ b2, const float* __restrict__ bfc,
         float* __restrict__ ws, float* __restrict__ out) {
    __shared__ float w2L[Hdim][Hdim + 1];   // 66 KB (also transpose tile)
    __shared__ unsigned short dl[1024];
    __shared__ unsigned flag[Anodes];
    __shared__ unsigned cntL[Anodes];
    __shared__ float plist[1024];
    __shared__ float Gr[Hdim];
    __shared__ float gred[Hdim];
    __shared__ int nz;
    __shared__ int sawS;

    const int tid = threadIdx.x;
    const int s = blockIdx.x;

    if (s >= Anodes) {
        if (s < Anodes + 4) {                // w1T strips
            const int k0 = (s - Anodes) * 32;
            for (int i = tid; i < 32 * 128; i += 256) {
                int r = i >> 7, c = i & 127;
                w2L[r][c] = w1[(k0 + r) * Hdim + c];
            }
            __syncthreads();
            short* o = (short*)(ws + WS_W1T);
            const int n = tid >> 1, j0 = (tid & 1) * 16;
            short tmp[16];
            #pragma unroll
            for (int j = 0; j < 16; ++j) tmp[j] = f2bf(w2L[j0 + j][n]);
            short8* dst = (short8*)(o + n * Hdim + k0 + j0);
            dst[0] = *(short8*)(tmp);
            dst[1] = *(short8*)(tmp + 8);
        } else {                             // init out with bias (overwrites poison)
            if (tid < Bbatch) out[tid] = bfc[0];
        }
        return;
    }

    for (int i = tid; i < Anodes; i += 256) { flag[i] = 0u; cntL[i] = 0u; }
    if (tid == 0) { nz = 0; sawS = 0; }
    __syncthreads();

    // stage w2 (no dependency on scans)
    for (int i = tid; i < Hdim * Hdim; i += 256)
        w2L[i >> 7][i & 127] = w2[i];

    const int4* s4 = (const int4*)ei;
    const int4* d4 = (const int4*)(ei + Eedges);
    // scan 1: collect dst's of edges with src==s
    for (int i = tid; i < Eedges / 4; i += 256) {
        int4 sv = s4[i];
        int4 dv = d4[i];
        int d;
        if ((sv.x & AMASK) == s) { d = dv.x & AMASK; dl[atomicAdd(&nz, 1)] = (unsigned short)d; flag[d] = 1u; }
        if ((sv.y & AMASK) == s) { d = dv.y & AMASK; dl[atomicAdd(&nz, 1)] = (unsigned short)d; flag[d] = 1u; }
        if ((sv.z & AMASK) == s) { d = dv.z & AMASK; dl[atomicAdd(&nz, 1)] = (unsigned short)d; flag[d] = 1u; }
        if ((sv.w & AMASK) == s) { d = dv.w & AMASK; dl[atomicAdd(&nz, 1)] = (unsigned short)d; flag[d] = 1u; }
    }
    __syncthreads();
    // scan 2: count flagged dst's; detect s as dst
    for (int i = tid; i < Eedges / 4; i += 256) {
        int4 dv = d4[i];
        int d;
        d = dv.x & AMASK; if (flag[d]) atomicAdd(&cntL[d], 1u); if (d == s) sawS = 1;
        d = dv.y & AMASK; if (flag[d]) atomicAdd(&cntL[d], 1u); if (d == s) sawS = 1;
        d = dv.z & AMASK; if (flag[d]) atomicAdd(&cntL[d], 1u); if (d == s) sawS = 1;
        d = dv.w & AMASK; if (flag[d]) atomicAdd(&cntL[d], 1u); if (d == s) sawS = 1;
    }
    __syncthreads();
    const int n = nz;
    for (int i = tid; i < n; i += 256)
        plist[i] = 1.0f / fmaxf((float)cntL[dl[i]], 1.0f);
    __syncthreads();

    const int k = tid & 127, half = tid >> 7;
    float g = 0.f;
    for (int i = half; i < n; i += 2)
        g += plist[i] * wfc[(size_t)dl[i] * Hdim + k];
    if (half) gred[k] = g;
    __syncthreads();
    if (!half) Gr[k] = g + gred[k];
    __syncthreads();

    // U[s,k] = sum_h w2[k,h] * Gr[h]  (f32 exact)
    float u = 0.f;
    const int h0 = half * 64;
    #pragma unroll 8
    for (int hh = h0; hh < h0 + 64; ++hh) u += w2L[k][hh] * Gr[hh];
    if (half) gred[k] = u;
    __syncthreads();
    if (!half) ws[WS_U + (size_t)s * Hdim + k] = u + gred[k];

    // c[s] = sawS ? b2 . wfc[s,:] : 0
    float cv = 0.f;
    if (tid < 128) cv = b2[tid] * wfc[(size_t)s * Hdim + tid];
    #pragma unroll
    for (int off = 32; off; off >>= 1) cv += __shfl_down(cv, off, 64);
    __syncthreads();            // gred free for reuse
    if (tid == 0)  gred[0] = cv;
    if (tid == 64) gred[1] = cv;
    __syncthreads();
    if (tid == 0) ws[WS_CARR + s] = sawS ? (gred[0] + gred[1]) : 0.f;
}

// n2: MFMA; block (b, chunk): partial + chunk-C -> atomicAdd out[b] directly.
__global__ __launch_bounds__(256)
void k_main(const float* __restrict__ x, const float* __restrict__ b1,
            const float* __restrict__ ws, float* __restrict__ out) {
    __shared__ short w1s[Hdim * Hdim];   // swizzled bf16 [n][k], 32 KB
    __shared__ float red[4];

    const int tid  = threadIdx.x;
    const int row0 = blockIdx.x * 64;
    const int b    = blockIdx.x >> 3;
    const int a0   = (blockIdx.x & 7) * 64;

    {
        const short8* gsrc = (const short8*)(ws + WS_W1T);
        for (int i = tid; i < 2048; i += 256) {
            short8 v = gsrc[i];
            int n = i >> 4;
            int byte = (i * 16) ^ ((n & 7) << 4);
            *(short8*)((char*)w1s + byte) = v;
        }
    }
    __syncthreads();

    const int w = tid >> 6;
    const int l = tid & 63;
    const int c = l & 15;
    const int g = l >> 4;

    const float* xrow = x + (size_t)(row0 + w * 16 + c) * Hdim;

    f32x4 acc[8];
    #pragma unroll
    for (int n = 0; n < 8; ++n) acc[n] = (f32x4){0.f, 0.f, 0.f, 0.f};

    #pragma unroll
    for (int ks = 0; ks < 4; ++ks) {
        const int k0 = ks * 32;
        float4 a_lo = *(const float4*)(xrow + k0 + 8 * g);
        float4 a_hi = *(const float4*)(xrow + k0 + 8 * g + 4);
        short8 a;
        a[0] = f2bf(a_lo.x); a[1] = f2bf(a_lo.y); a[2] = f2bf(a_lo.z); a[3] = f2bf(a_lo.w);
        a[4] = f2bf(a_hi.x); a[5] = f2bf(a_hi.y); a[6] = f2bf(a_hi.z); a[7] = f2bf(a_hi.w);
        #pragma unroll
        for (int n = 0; n < 8; ++n) {
            int byte = (((n * 16 + c) << 8) + ((k0 + 8 * g) << 1)) ^ ((c & 7) << 4);
            short8 bf = *(short8*)((char*)w1s + byte);
            acc[n] = __builtin_amdgcn_mfma_f32_16x16x32_bf16(a, bf, acc[n], 0, 0, 0);
        }
    }

    float part = 0.f;
    const float* U = ws + WS_U;
    #pragma unroll
    for (int n = 0; n < 8; ++n) {
        const int colg = n * 16 + c;
        const float bv = b1[colg];
        #pragma unroll
        for (int r = 0; r < 4; ++r) {
            const int arow = a0 + w * 16 + g * 4 + r;
            float z = acc[n][r] + bv;
            part += fmaxf(z, 0.f) * U[arow * Hdim + colg];
        }
    }
    #pragma unroll
    for (int off = 32; off; off >>= 1) part += __shfl_down(part, off, 64);
    if (l == 0) red[w] = part;
    __syncthreads();

    // fold per-chunk C contribution; single atomic per block into out
    float cw = 0.f;
    if (tid < 64) cw = ws[WS_CARR + a0 + tid];
    #pragma unroll
    for (int off = 32; off; off >>= 1) cw += __shfl_down(cw, off, 64);
    if (tid == 0)
        atomicAdd(out + b, red[0] + red[1] + red[2] + red[3] + cw);
}

extern "C" void kernel_launch(void* const* d_in, const int* in_sizes, int n_in,
                              void* d_out, int out_size, void* d_ws, size_t ws_size,
                              hipStream_t stream) {
    const float* x   = (const float*)d_in[0];
    // d_in[1] = pos (unused)
    const int*   ei  = (const int*)d_in[2];
    const float* w1  = (const float*)d_in[3];
    const float* b1  = (const float*)d_in[4];
    const float* w2  = (const float*)d_in[5];
    const float* b2  = (const float*)d_in[6];
    const float* wfc = (const float*)d_in[7];
    const float* bfc = (const float*)d_in[8];
    float* out = (float*)d_out;
    float* ws  = (float*)d_ws;

    hipLaunchKernelGGL(k_G,    dim3(517), dim3(256), 0, stream,
                       ei, w1, w2, wfc, b2, bfc, ws, out);
    hipLaunchKernelGGL(k_main, dim3(512), dim3(256), 0, stream, x, b1, ws, out);
}

// Round 13
// 26.281 us; speedup vs baseline: 5.7157x; 1.2629x over previous
//
#include <hip/hip_runtime.h>

#define Hdim   128
#define Anodes 512
#define Bbatch 64
#define Eedges 16384
#define AMASK  (Anodes - 1)

// ws float offsets
#define WS_W1T  0        // bf16[128][128] stored as 8192 floats
#define WS_U    8192     // f32[512][128]
#define WS_CARR 73728    // f32[512] per-node C contribution

typedef __attribute__((ext_vector_type(8))) short short8;
typedef __attribute__((ext_vector_type(4))) float f32x4;

__device__ __forceinline__ short f2bf(float f) {
    union { float f; unsigned u; } v; v.f = f;
    unsigned r = v.u + 0x7FFFu + ((v.u >> 16) & 1u);
    return (short)(r >> 16);
}

// n1 (512 threads/block): blocks 0..511 (s): per-source aggregation -> U[s,:], CARR[s]
//     blocks 512..515: w1 -> bf16 w1T strip transpose
//     block 516: out[b] = bfc (poison-overwrite + bias init)
__global__ __launch_bounds__(512)
void k_G(const int* __restrict__ ei, const float* __restrict__ w1,
         const float* __restrict__ w2, const float* __restrict__ wfc,
         const float* __restrict__ b2, const float* __restrict__ bfc,
         float* __restrict__ ws, float* __restrict__ out) {
    __shared__ float w2L[Hdim][Hdim + 1];   // 66 KB (rows 0..31 double as transpose tile)
    __shared__ unsigned short dl[1024];
    __shared__ unsigned flag[Anodes];
    __shared__ unsigned cntL[Anodes];
    __shared__ float plist[1024];
    __shared__ float Gr[Hdim];
    __shared__ float qred[4][Hdim];
    __shared__ int nz;
    __shared__ int sawS;

    const int tid = threadIdx.x;
    const int s = blockIdx.x;

    if (s >= Anodes) {
        if (s < Anodes + 4) {                // w1T strips
            const int k0 = (s - Anodes) * 32;
            for (int i = tid; i < 32 * 128; i += 512) {
                int r = i >> 7, c = i & 127;
                w2L[r][c] = w1[(k0 + r) * Hdim + c];
            }
            __syncthreads();
            if (tid < 256) {
                short* o = (short*)(ws + WS_W1T);
                const int n = tid >> 1, j0 = (tid & 1) * 16;
                short tmp[16];
                #pragma unroll
                for (int j = 0; j < 16; ++j) tmp[j] = f2bf(w2L[j0 + j][n]);
                short8* dst = (short8*)(o + n * Hdim + k0 + j0);
                dst[0] = *(short8*)(tmp);
                dst[1] = *(short8*)(tmp + 8);
            }
        } else {                             // init out with bias (overwrites poison)
            if (tid < Bbatch) out[tid] = bfc[0];
        }
        return;
    }

    for (int i = tid; i < Anodes; i += 512) { flag[i] = 0u; cntL[i] = 0u; }
    if (tid == 0) { nz = 0; sawS = 0; }
    __syncthreads();

    // stage w2 (no dependency on scans)
    for (int i = tid; i < Hdim * Hdim; i += 512)
        w2L[i >> 7][i & 127] = w2[i];

    const int4* s4 = (const int4*)ei;
    const int4* d4 = (const int4*)(ei + Eedges);
    // scan 1: collect dst's of edges with src==s
    for (int i = tid; i < Eedges / 4; i += 512) {
        int4 sv = s4[i];
        int4 dv = d4[i];
        int d;
        if ((sv.x & AMASK) == s) { d = dv.x & AMASK; dl[atomicAdd(&nz, 1)] = (unsigned short)d; flag[d] = 1u; }
        if ((sv.y & AMASK) == s) { d = dv.y & AMASK; dl[atomicAdd(&nz, 1)] = (unsigned short)d; flag[d] = 1u; }
        if ((sv.z & AMASK) == s) { d = dv.z & AMASK; dl[atomicAdd(&nz, 1)] = (unsigned short)d; flag[d] = 1u; }
        if ((sv.w & AMASK) == s) { d = dv.w & AMASK; dl[atomicAdd(&nz, 1)] = (unsigned short)d; flag[d] = 1u; }
    }
    __syncthreads();
    // scan 2: count flagged dst's; detect s as dst
    for (int i = tid; i < Eedges / 4; i += 512) {
        int4 dv = d4[i];
        int d;
        d = dv.x & AMASK; if (flag[d]) atomicAdd(&cntL[d], 1u); if (d == s) sawS = 1;
        d = dv.y & AMASK; if (flag[d]) atomicAdd(&cntL[d], 1u); if (d == s) sawS = 1;
        d = dv.z & AMASK; if (flag[d]) atomicAdd(&cntL[d], 1u); if (d == s) sawS = 1;
        d = dv.w & AMASK; if (flag[d]) atomicAdd(&cntL[d], 1u); if (d == s) sawS = 1;
    }
    __syncthreads();
    const int n = nz;
    for (int i = tid; i < n; i += 512)
        plist[i] = 1.0f / fmaxf((float)cntL[dl[i]], 1.0f);
    __syncthreads();

    const int k = tid & 127, q = tid >> 7;   // quarter 0..3
    float g = 0.f;
    for (int i = q; i < n; i += 4)
        g += plist[i] * wfc[(size_t)dl[i] * Hdim + k];
    qred[q][k] = g;
    __syncthreads();
    if (q == 0) Gr[k] = qred[0][k] + qred[1][k] + qred[2][k] + qred[3][k];
    __syncthreads();

    // U[s,k] = sum_h w2[k,h] * Gr[h]  (f32 exact), 4-way split over h
    float u = 0.f;
    const int h0 = q * 32;
    #pragma unroll 8
    for (int hh = h0; hh < h0 + 32; ++hh) u += w2L[k][hh] * Gr[hh];
    qred[q][k] = u;
    __syncthreads();
    if (q == 0) ws[WS_U + (size_t)s * Hdim + k] = qred[0][k] + qred[1][k] + qred[2][k] + qred[3][k];

    // c[s] = sawS ? b2 . wfc[s,:] : 0
    float cv = 0.f;
    if (tid < 128) cv = b2[tid] * wfc[(size_t)s * Hdim + tid];
    #pragma unroll
    for (int off = 32; off; off >>= 1) cv += __shfl_down(cv, off, 64);
    __syncthreads();            // qred free for reuse
    if (tid == 0)  qred[0][0] = cv;
    if (tid == 64) qred[0][1] = cv;
    __syncthreads();
    if (tid == 0) ws[WS_CARR + s] = sawS ? (qred[0][0] + qred[0][1]) : 0.f;
}

// n2: MFMA; block (b, chunk): partial + chunk-C -> atomicAdd out[b] directly.
__global__ __launch_bounds__(256)
void k_main(const float* __restrict__ x, const float* __restrict__ b1,
            const float* __restrict__ ws, float* __restrict__ out) {
    __shared__ short w1s[Hdim * Hdim];   // swizzled bf16 [n][k], 32 KB
    __shared__ float red[4];

    const int tid  = threadIdx.x;
    const int row0 = blockIdx.x * 64;
    const int b    = blockIdx.x >> 3;
    const int a0   = (blockIdx.x & 7) * 64;

    {
        const short8* gsrc = (const short8*)(ws + WS_W1T);
        for (int i = tid; i < 2048; i += 256) {
            short8 v = gsrc[i];
            int n = i >> 4;
            int byte = (i * 16) ^ ((n & 7) << 4);
            *(short8*)((char*)w1s + byte) = v;
        }
    }
    __syncthreads();

    const int w = tid >> 6;
    const int l = tid & 63;
    const int c = l & 15;
    const int g = l >> 4;

    const float* xrow = x + (size_t)(row0 + w * 16 + c) * Hdim;

    f32x4 acc[8];
    #pragma unroll
    for (int n = 0; n < 8; ++n) acc[n] = (f32x4){0.f, 0.f, 0.f, 0.f};

    #pragma unroll
    for (int ks = 0; ks < 4; ++ks) {
        const int k0 = ks * 32;
        float4 a_lo = *(const float4*)(xrow + k0 + 8 * g);
        float4 a_hi = *(const float4*)(xrow + k0 + 8 * g + 4);
        short8 a;
        a[0] = f2bf(a_lo.x); a[1] = f2bf(a_lo.y); a[2] = f2bf(a_lo.z); a[3] = f2bf(a_lo.w);
        a[4] = f2bf(a_hi.x); a[5] = f2bf(a_hi.y); a[6] = f2bf(a_hi.z); a[7] = f2bf(a_hi.w);
        #pragma unroll
        for (int n = 0; n < 8; ++n) {
            int byte = (((n * 16 + c) << 8) + ((k0 + 8 * g) << 1)) ^ ((c & 7) << 4);
            short8 bf = *(short8*)((char*)w1s + byte);
            acc[n] = __builtin_amdgcn_mfma_f32_16x16x32_bf16(a, bf, acc[n], 0, 0, 0);
        }
    }

    float part = 0.f;
    const float* U = ws + WS_U;
    #pragma unroll
    for (int n = 0; n < 8; ++n) {
        const int colg = n * 16 + c;
        const float bv = b1[colg];
        #pragma unroll
        for (int r = 0; r < 4; ++r) {
            const int arow = a0 + w * 16 + g * 4 + r;
            float z = acc[n][r] + bv;
            part += fmaxf(z, 0.f) * U[arow * Hdim + colg];
        }
    }
    #pragma unroll
    for (int off = 32; off; off >>= 1) part += __shfl_down(part, off, 64);
    if (l == 0) red[w] = part;
    __syncthreads();

    // fold per-chunk C contribution; single atomic per block into out
    float cw = 0.f;
    if (tid < 64) cw = ws[WS_CARR + a0 + tid];
    #pragma unroll
    for (int off = 32; off; off >>= 1) cw += __shfl_down(cw, off, 64);
    if (tid == 0)
        atomicAdd(out + b, red[0] + red[1] + red[2] + red[3] + cw);
}

extern "C" void kernel_launch(void* const* d_in, const int* in_sizes, int n_in,
                              void* d_out, int out_size, void* d_ws, size_t ws_size,
                              hipStream_t stream) {
    const float* x   = (const float*)d_in[0];
    // d_in[1] = pos (unused)
    const int*   ei  = (const int*)d_in[2];
    const float* w1  = (const float*)d_in[3];
    const float* b1  = (const float*)d_in[4];
    const float* w2  = (const float*)d_in[5];
    const float* b2  = (const float*)d_in[6];
    const float* wfc = (const float*)d_in[7];
    const float* bfc = (const float*)d_in[8];
    float* out = (float*)d_out;
    float* ws  = (float*)d_ws;

    hipLaunchKernelGGL(k_G,    dim3(517), dim3(512), 0, stream,
                       ei, w1, w2, wfc, b2, bfc, ws, out);
    hipLaunchKernelGGL(k_main, dim3(512), dim3(256), 0, stream, x, b1, ws, out);
}

// Round 14
// 24.239 us; speedup vs baseline: 6.1972x; 1.0842x over previous
//
#include <hip/hip_runtime.h>

#define Hdim   128
#define Anodes 512
#define Bbatch 64
#define Eedges 16384
#define AMASK  (Anodes - 1)

// ws float offsets
#define WS_W1T  0        // bf16[128][128] stored as 8192 floats
#define WS_U    8192     // f32[512][128]
#define WS_CARR 73728    // f32[512] per-node C contribution

typedef __attribute__((ext_vector_type(8))) short short8;
typedef __attribute__((ext_vector_type(4))) float f32x4;

__device__ __forceinline__ short f2bf(float f) {
    union { float f; unsigned u; } v; v.f = f;
    unsigned r = v.u + 0x7FFFu + ((v.u >> 16) & 1u);
    return (short)(r >> 16);
}

// n1 (512 threads/block): blocks 0..511 (s): per-source aggregation -> U[s,:], CARR[s]
//     blocks 512..515: w1 -> bf16 w1T strip transpose
//     block 516: out[b] = bfc (poison-overwrite + bias init)
__global__ __launch_bounds__(512)
void k_G(const int* __restrict__ ei, const float* __restrict__ w1,
         const float* __restrict__ w2, const float* __restrict__ wfc,
         const float* __restrict__ b2, const float* __restrict__ bfc,
         float* __restrict__ ws, float* __restrict__ out) {
    __shared__ float w2L[Hdim][Hdim + 1];   // 66 KB (rows 0..31 double as transpose tile)
    __shared__ unsigned short dl[1024];
    __shared__ unsigned cntL[Anodes];
    __shared__ float plist[1024];
    __shared__ float Gr[Hdim];
    __shared__ float qred[4][Hdim];
    __shared__ int nz;
    __shared__ int sawS;

    const int tid = threadIdx.x;
    const int s = blockIdx.x;

    if (s >= Anodes) {
        if (s < Anodes + 4) {                // w1T strips
            const int k0 = (s - Anodes) * 32;
            for (int i = tid; i < 32 * 128; i += 512) {
                int r = i >> 7, c = i & 127;
                w2L[r][c] = w1[(k0 + r) * Hdim + c];
            }
            __syncthreads();
            if (tid < 256) {
                short* o = (short*)(ws + WS_W1T);
                const int n = tid >> 1, j0 = (tid & 1) * 16;
                short tmp[16];
                #pragma unroll
                for (int j = 0; j < 16; ++j) tmp[j] = f2bf(w2L[j0 + j][n]);
                short8* dst = (short8*)(o + n * Hdim + k0 + j0);
                dst[0] = *(short8*)(tmp);
                dst[1] = *(short8*)(tmp + 8);
            }
        } else {                             // init out with bias (overwrites poison)
            if (tid < Bbatch) out[tid] = bfc[0];
        }
        return;
    }

    for (int i = tid; i < Anodes; i += 512) cntL[i] = 0u;
    if (tid == 0) { nz = 0; sawS = 0; }
    __syncthreads();

    // stage w2 (no dependency on scan), float4
    {
        const float4* w2v = (const float4*)w2;
        for (int i = tid; i < (Hdim * Hdim) / 4; i += 512) {
            float4 v = w2v[i];
            float* dst = &w2L[i >> 5][(i & 31) * 4];
            dst[0] = v.x; dst[1] = v.y; dst[2] = v.z; dst[3] = v.w;
        }
    }

    // SINGLE fused edge scan: global dst histogram + this-source dst collection
    const int4* s4 = (const int4*)ei;
    const int4* d4 = (const int4*)(ei + Eedges);
    for (int i = tid; i < Eedges / 4; i += 512) {
        int4 sv = s4[i];
        int4 dv = d4[i];
        int d;
        d = dv.x & AMASK; atomicAdd(&cntL[d], 1u); if (d == s) sawS = 1;
        if ((sv.x & AMASK) == s) dl[atomicAdd(&nz, 1)] = (unsigned short)d;
        d = dv.y & AMASK; atomicAdd(&cntL[d], 1u); if (d == s) sawS = 1;
        if ((sv.y & AMASK) == s) dl[atomicAdd(&nz, 1)] = (unsigned short)d;
        d = dv.z & AMASK; atomicAdd(&cntL[d], 1u); if (d == s) sawS = 1;
        if ((sv.z & AMASK) == s) dl[atomicAdd(&nz, 1)] = (unsigned short)d;
        d = dv.w & AMASK; atomicAdd(&cntL[d], 1u); if (d == s) sawS = 1;
        if ((sv.w & AMASK) == s) dl[atomicAdd(&nz, 1)] = (unsigned short)d;
    }
    __syncthreads();
    const int n = nz;
    for (int i = tid; i < n; i += 512)
        plist[i] = 1.0f / fmaxf((float)cntL[dl[i]], 1.0f);
    __syncthreads();

    const int k = tid & 127, q = tid >> 7;   // quarter 0..3
    float g = 0.f;
    for (int i = q; i < n; i += 4)
        g += plist[i] * wfc[(size_t)dl[i] * Hdim + k];
    qred[q][k] = g;
    __syncthreads();
    if (q == 0) Gr[k] = qred[0][k] + qred[1][k] + qred[2][k] + qred[3][k];
    __syncthreads();

    // U[s,k] = sum_h w2[k,h] * Gr[h]  (f32 exact), 4-way split over h
    float u = 0.f;
    const int h0 = q * 32;
    #pragma unroll 8
    for (int hh = h0; hh < h0 + 32; ++hh) u += w2L[k][hh] * Gr[hh];
    qred[q][k] = u;
    __syncthreads();
    if (q == 0) ws[WS_U + (size_t)s * Hdim + k] = qred[0][k] + qred[1][k] + qred[2][k] + qred[3][k];

    // c[s] = sawS ? b2 . wfc[s,:] : 0
    float cv = 0.f;
    if (tid < 128) cv = b2[tid] * wfc[(size_t)s * Hdim + tid];
    #pragma unroll
    for (int off = 32; off; off >>= 1) cv += __shfl_down(cv, off, 64);
    __syncthreads();            // qred free for reuse
    if (tid == 0)  qred[0][0] = cv;
    if (tid == 64) qred[0][1] = cv;
    __syncthreads();
    if (tid == 0) ws[WS_CARR + s] = sawS ? (qred[0][0] + qred[0][1]) : 0.f;
}

// n2: MFMA; block (b, chunk): partial + chunk-C -> atomicAdd out[b] directly.
__global__ __launch_bounds__(256)
void k_main(const float* __restrict__ x, const float* __restrict__ b1,
            const float* __restrict__ ws, float* __restrict__ out) {
    __shared__ short w1s[Hdim * Hdim];   // swizzled bf16 [n][k], 32 KB
    __shared__ float red[4];

    const int tid  = threadIdx.x;
    const int row0 = blockIdx.x * 64;
    const int b    = blockIdx.x >> 3;
    const int a0   = (blockIdx.x & 7) * 64;

    {
        const short8* gsrc = (const short8*)(ws + WS_W1T);
        for (int i = tid; i < 2048; i += 256) {
            short8 v = gsrc[i];
            int n = i >> 4;
            int byte = (i * 16) ^ ((n & 7) << 4);
            *(short8*)((char*)w1s + byte) = v;
        }
    }
    __syncthreads();

    const int w = tid >> 6;
    const int l = tid & 63;
    const int c = l & 15;
    const int g = l >> 4;

    const float* xrow = x + (size_t)(row0 + w * 16 + c) * Hdim;

    f32x4 acc[8];
    #pragma unroll
    for (int n = 0; n < 8; ++n) acc[n] = (f32x4){0.f, 0.f, 0.f, 0.f};

    #pragma unroll
    for (int ks = 0; ks < 4; ++ks) {
        const int k0 = ks * 32;
        float4 a_lo = *(const float4*)(xrow + k0 + 8 * g);
        float4 a_hi = *(const float4*)(xrow + k0 + 8 * g + 4);
        short8 a;
        a[0] = f2bf(a_lo.x); a[1] = f2bf(a_lo.y); a[2] = f2bf(a_lo.z); a[3] = f2bf(a_lo.w);
        a[4] = f2bf(a_hi.x); a[5] = f2bf(a_hi.y); a[6] = f2bf(a_hi.z); a[7] = f2bf(a_hi.w);
        #pragma unroll
        for (int n = 0; n < 8; ++n) {
            int byte = (((n * 16 + c) << 8) + ((k0 + 8 * g) << 1)) ^ ((c & 7) << 4);
            short8 bf = *(short8*)((char*)w1s + byte);
            acc[n] = __builtin_amdgcn_mfma_f32_16x16x32_bf16(a, bf, acc[n], 0, 0, 0);
        }
    }

    float part = 0.f;
    const float* U = ws + WS_U;
    #pragma unroll
    for (int n = 0; n < 8; ++n) {
        const int colg = n * 16 + c;
        const float bv = b1[colg];
        #pragma unroll
        for (int r = 0; r < 4; ++r) {
            const int arow = a0 + w * 16 + g * 4 + r;
            float z = acc[n][r] + bv;
            part += fmaxf(z, 0.f) * U[arow * Hdim + colg];
        }
    }
    #pragma unroll
    for (int off = 32; off; off >>= 1) part += __shfl_down(part, off, 64);
    if (l == 0) red[w] = part;
    __syncthreads();

    // fold per-chunk C contribution; single atomic per block into out
    float cw = 0.f;
    if (tid < 64) cw = ws[WS_CARR + a0 + tid];
    #pragma unroll
    for (int off = 32; off; off >>= 1) cw += __shfl_down(cw, off, 64);
    if (tid == 0)
        atomicAdd(out + b, red[0] + red[1] + red[2] + red[3] + cw);
}

extern "C" void kernel_launch(void* const* d_in, const int* in_sizes, int n_in,
                              void* d_out, int out_size, void* d_ws, size_t ws_size,
                              hipStream_t stream) {
    const float* x   = (const float*)d_in[0];
    // d_in[1] = pos (unused)
    const int*   ei  = (const int*)d_in[2];
    const float* w1  = (const float*)d_in[3];
    const float* b1  = (const float*)d_in[4];
    const float* w2  = (const float*)d_in[5];
    const float* b2  = (const float*)d_in[6];
    const float* wfc = (const float*)d_in[7];
    const float* bfc = (const float*)d_in[8];
    float* out = (float*)d_out;
    float* ws  = (float*)d_ws;

    hipLaunchKernelGGL(k_G,    dim3(517), dim3(512), 0, stream,
                       ei, w1, w2, wfc, b2, bfc, ws, out);
    hipLaunchKernelGGL(k_main, dim3(512), dim3(256), 0, stream, x, b1, ws, out);
}

// Round 15
// 23.211 us; speedup vs baseline: 6.4717x; 1.0443x over previous
//
#include <hip/hip_runtime.h>

#define Hdim   128
#define Anodes 512
#define Bbatch 64
#define Eedges 16384
#define AMASK  (Anodes - 1)

// ws float offsets
#define WS_W1T  0        // bf16[128][128] stored as 8192 floats
#define WS_U    8192     // f32[512][128]
#define WS_CARR 73728    // f32[512] per-node C contribution

typedef __attribute__((ext_vector_type(8))) short short8;
typedef __attribute__((ext_vector_type(4))) float f32x4;

__device__ __forceinline__ short f2bf(float f) {
    union { float f; unsigned u; } v; v.f = f;
    unsigned r = v.u + 0x7FFFu + ((v.u >> 16) & 1u);
    return (short)(r >> 16);
}

// n1 (1024 threads/block): blocks 0..255: TWO sources each (s0=2*blk, s0+1):
//   one shared edge scan -> global dst histogram + both sources' dst lists,
//   then per-half gather G -> U[s,:] = w2 @ G (f32 exact), CARR[s].
// blocks 256..259: w1 -> bf16 w1T strip transpose
// block 260: out[b] = bfc (poison-overwrite + bias init)
__global__ __launch_bounds__(1024)
void k_G(const int* __restrict__ ei, const float* __restrict__ w1,
         const float* __restrict__ w2, const float* __restrict__ wfc,
         const float* __restrict__ b2, const float* __restrict__ bfc,
         float* __restrict__ ws, float* __restrict__ out) {
    __shared__ float w2L[Hdim][Hdim + 1];     // 66 KB (rows 0..31 double as transpose tile)
    __shared__ unsigned short dl[2][1024];    // 4 KB
    __shared__ unsigned cntL[Anodes];         // 2 KB
    __shared__ float plist[2][1024];          // 8 KB
    __shared__ float Gr[2][Hdim];             // 1 KB
    __shared__ float qred[2][4][Hdim];        // 4 KB
    __shared__ int nz[2];
    __shared__ int saw[2];

    const int tid = threadIdx.x;
    const int blk = blockIdx.x;

    if (blk >= 256) {
        if (blk < 260) {                     // w1T strips
            const int k0 = (blk - 256) * 32;
            for (int i = tid; i < 32 * 128; i += 1024) {
                int r = i >> 7, c = i & 127;
                w2L[r][c] = w1[(k0 + r) * Hdim + c];
            }
            __syncthreads();
            if (tid < 256) {
                short* o = (short*)(ws + WS_W1T);
                const int n = tid >> 1, j0 = (tid & 1) * 16;
                short tmp[16];
                #pragma unroll
                for (int j = 0; j < 16; ++j) tmp[j] = f2bf(w2L[j0 + j][n]);
                short8* dst = (short8*)(o + n * Hdim + k0 + j0);
                dst[0] = *(short8*)(tmp);
                dst[1] = *(short8*)(tmp + 8);
            }
        } else {                             // init out with bias (overwrites poison)
            if (tid < Bbatch) out[tid] = bfc[0];
        }
        return;
    }

    const int s0 = blk * 2;

    for (int i = tid; i < Anodes; i += 1024) cntL[i] = 0u;
    if (tid < 2) { nz[tid] = 0; saw[tid] = 0; }
    __syncthreads();

    // stage w2 (no dependency on scan), float4
    {
        const float4* w2v = (const float4*)w2;
        for (int i = tid; i < (Hdim * Hdim) / 4; i += 1024) {
            float4 v = w2v[i];
            float* dst = &w2L[i >> 5][(i & 31) * 4];
            dst[0] = v.x; dst[1] = v.y; dst[2] = v.z; dst[3] = v.w;
        }
    }

    // SINGLE shared edge scan: global dst histogram + both sources' dst lists
    const int4* s4 = (const int4*)ei;
    const int4* d4 = (const int4*)(ei + Eedges);
    for (int i = tid; i < Eedges / 4; i += 1024) {   // 4 iterations
        int4 sv = s4[i];
        int4 dv = d4[i];
        int d, ss;
        d = dv.x & AMASK; atomicAdd(&cntL[d], 1u);
        if (d == s0) saw[0] = 1; else if (d == s0 + 1) saw[1] = 1;
        ss = sv.x & AMASK;
        if (ss == s0) dl[0][atomicAdd(&nz[0], 1)] = (unsigned short)d;
        else if (ss == s0 + 1) dl[1][atomicAdd(&nz[1], 1)] = (unsigned short)d;
        d = dv.y & AMASK; atomicAdd(&cntL[d], 1u);
        if (d == s0) saw[0] = 1; else if (d == s0 + 1) saw[1] = 1;
        ss = sv.y & AMASK;
        if (ss == s0) dl[0][atomicAdd(&nz[0], 1)] = (unsigned short)d;
        else if (ss == s0 + 1) dl[1][atomicAdd(&nz[1], 1)] = (unsigned short)d;
        d = dv.z & AMASK; atomicAdd(&cntL[d], 1u);
        if (d == s0) saw[0] = 1; else if (d == s0 + 1) saw[1] = 1;
        ss = sv.z & AMASK;
        if (ss == s0) dl[0][atomicAdd(&nz[0], 1)] = (unsigned short)d;
        else if (ss == s0 + 1) dl[1][atomicAdd(&nz[1], 1)] = (unsigned short)d;
        d = dv.w & AMASK; atomicAdd(&cntL[d], 1u);
        if (d == s0) saw[0] = 1; else if (d == s0 + 1) saw[1] = 1;
        ss = sv.w & AMASK;
        if (ss == s0) dl[0][atomicAdd(&nz[0], 1)] = (unsigned short)d;
        else if (ss == s0 + 1) dl[1][atomicAdd(&nz[1], 1)] = (unsigned short)d;
    }
    __syncthreads();

    const int h  = tid >> 9;        // half: source s0+h
    const int t5 = tid & 511;
    const int n  = nz[h];
    for (int i = t5; i < n; i += 512)
        plist[h][i] = 1.0f / fmaxf((float)cntL[dl[h][i]], 1.0f);
    __syncthreads();

    const int k = tid & 127, q = (tid >> 7) & 3;   // quarter within half
    float g = 0.f;
    for (int i = q; i < n; i += 4)
        g += plist[h][i] * wfc[(size_t)dl[h][i] * Hdim + k];
    qred[h][q][k] = g;
    __syncthreads();
    if (q == 0) Gr[h][k] = qred[h][0][k] + qred[h][1][k] + qred[h][2][k] + qred[h][3][k];
    __syncthreads();

    // U[s0+h,k] = sum_hh w2[k,hh] * Gr[h][hh]  (f32 exact), 4-way split
    float u = 0.f;
    const int h0 = q * 32;
    #pragma unroll 8
    for (int hh = h0; hh < h0 + 32; ++hh) u += w2L[k][hh] * Gr[h][hh];
    qred[h][q][k] = u;
    __syncthreads();
    if (q == 0)
        ws[WS_U + (size_t)(s0 + h) * Hdim + k] =
            qred[h][0][k] + qred[h][1][k] + qred[h][2][k] + qred[h][3][k];

    // c[s0+h] = saw[h] ? b2 . wfc[s0+h,:] : 0
    float cv = 0.f;
    if (t5 < 128) cv = b2[t5] * wfc[(size_t)(s0 + h) * Hdim + t5];
    #pragma unroll
    for (int off = 32; off; off >>= 1) cv += __shfl_down(cv, off, 64);
    __syncthreads();            // qred free for reuse
    if (t5 == 0)  qred[h][0][0] = cv;
    if (t5 == 64) qred[h][0][1] = cv;
    __syncthreads();
    if (t5 == 0) ws[WS_CARR + s0 + h] = saw[h] ? (qred[h][0][0] + qred[h][0][1]) : 0.f;
}

// n2: MFMA; block (b, chunk): partial + chunk-C -> atomicAdd out[b] directly.
__global__ __launch_bounds__(256)
void k_main(const float* __restrict__ x, const float* __restrict__ b1,
            const float* __restrict__ ws, float* __restrict__ out) {
    __shared__ short w1s[Hdim * Hdim];   // swizzled bf16 [n][k], 32 KB
    __shared__ float red[4];

    const int tid  = threadIdx.x;
    const int row0 = blockIdx.x * 64;
    const int b    = blockIdx.x >> 3;
    const int a0   = (blockIdx.x & 7) * 64;

    {
        const short8* gsrc = (const short8*)(ws + WS_W1T);
        for (int i = tid; i < 2048; i += 256) {
            short8 v = gsrc[i];
            int n = i >> 4;
            int byte = (i * 16) ^ ((n & 7) << 4);
            *(short8*)((char*)w1s + byte) = v;
        }
    }
    __syncthreads();

    const int w = tid >> 6;
    const int l = tid & 63;
    const int c = l & 15;
    const int g = l >> 4;

    const float* xrow = x + (size_t)(row0 + w * 16 + c) * Hdim;

    f32x4 acc[8];
    #pragma unroll
    for (int n = 0; n < 8; ++n) acc[n] = (f32x4){0.f, 0.f, 0.f, 0.f};

    #pragma unroll
    for (int ks = 0; ks < 4; ++ks) {
        const int k0 = ks * 32;
        float4 a_lo = *(const float4*)(xrow + k0 + 8 * g);
        float4 a_hi = *(const float4*)(xrow + k0 + 8 * g + 4);
        short8 a;
        a[0] = f2bf(a_lo.x); a[1] = f2bf(a_lo.y); a[2] = f2bf(a_lo.z); a[3] = f2bf(a_lo.w);
        a[4] = f2bf(a_hi.x); a[5] = f2bf(a_hi.y); a[6] = f2bf(a_hi.z); a[7] = f2bf(a_hi.w);
        #pragma unroll
        for (int n = 0; n < 8; ++n) {
            int byte = (((n * 16 + c) << 8) + ((k0 + 8 * g) << 1)) ^ ((c & 7) << 4);
            short8 bf = *(short8*)((char*)w1s + byte);
            acc[n] = __builtin_amdgcn_mfma_f32_16x16x32_bf16(a, bf, acc[n], 0, 0, 0);
        }
    }

    float part = 0.f;
    const float* U = ws + WS_U;
    #pragma unroll
    for (int n = 0; n < 8; ++n) {
        const int colg = n * 16 + c;
        const float bv = b1[colg];
        #pragma unroll
        for (int r = 0; r < 4; ++r) {
            const int arow = a0 + w * 16 + g * 4 + r;
            float z = acc[n][r] + bv;
            part += fmaxf(z, 0.f) * U[arow * Hdim + colg];
        }
    }
    #pragma unroll
    for (int off = 32; off; off >>= 1) part += __shfl_down(part, off, 64);
    if (l == 0) red[w] = part;
    __syncthreads();

    // fold per-chunk C contribution; single atomic per block into out
    float cw = 0.f;
    if (tid < 64) cw = ws[WS_CARR + a0 + tid];
    #pragma unroll
    for (int off = 32; off; off >>= 1) cw += __shfl_down(cw, off, 64);
    if (tid == 0)
        atomicAdd(out + b, red[0] + red[1] + red[2] + red[3] + cw);
}

extern "C" void kernel_launch(void* const* d_in, const int* in_sizes, int n_in,
                              void* d_out, int out_size, void* d_ws, size_t ws_size,
                              hipStream_t stream) {
    const float* x   = (const float*)d_in[0];
    // d_in[1] = pos (unused)
    const int*   ei  = (const int*)d_in[2];
    const float* w1  = (const float*)d_in[3];
    const float* b1  = (const float*)d_in[4];
    const float* w2  = (const float*)d_in[5];
    const float* b2  = (const float*)d_in[6];
    const float* wfc = (const float*)d_in[7];
    const float* bfc = (const float*)d_in[8];
    float* out = (float*)d_out;
    float* ws  = (float*)d_ws;

    hipLaunchKernelGGL(k_G,    dim3(261), dim3(1024), 0, stream,
                       ei, w1, w2, wfc, b2, bfc, ws, out);
    hipLaunchKernelGGL(k_main, dim3(512), dim3(256), 0, stream, x, b1, ws, out);
}

// Round 20
// 23.193 us; speedup vs baseline: 6.4768x; 1.0008x over previous
//
#include <hip/hip_runtime.h>

#define Hdim   128
#define Anodes 512
#define Bbatch 64
#define Eedges 16384
#define AMASK  (Anodes - 1)

// ws float offsets
#define WS_W1T  0        // bf16[128][128] stored as 8192 floats
#define WS_U    8192     // f32[512][128]
#define WS_CARR 73728    // f32[512] per-node C contribution

typedef __attribute__((ext_vector_type(8))) short short8;
typedef __attribute__((ext_vector_type(4))) float f32x4;

__device__ __forceinline__ short f2bf(float f) {
    union { float f; unsigned u; } v; v.f = f;
    unsigned r = v.u + 0x7FFFu + ((v.u >> 16) & 1u);
    return (short)(r >> 16);
}

// n1 (1024 threads/block): blocks 0..255: TWO sources each (s0=2*blk, s0+1):
//   one shared edge scan -> global dst histogram + both sources' dst lists,
//   then per-half gather G -> U[s,:] = w2 @ G (f32 exact), CARR[s].
// blocks 256..259: w1 -> bf16 w1T strip transpose
// block 260: out[b] = bfc (poison-overwrite + bias init)
__global__ __launch_bounds__(1024)
void k_G(const int* __restrict__ ei, const float* __restrict__ w1,
         const float* __restrict__ w2, const float* __restrict__ wfc,
         const float* __restrict__ b2, const float* __restrict__ bfc,
         float* __restrict__ ws, float* __restrict__ out) {
    __shared__ float w2L[Hdim][Hdim + 1];     // 66 KB (rows 0..31 double as transpose tile)
    __shared__ unsigned short dl[2][1024];    // 4 KB
    __shared__ unsigned cntL[Anodes];         // 2 KB
    __shared__ float plist[2][1024];          // 8 KB
    __shared__ float Gr[2][Hdim];             // 1 KB
    __shared__ float qred[2][4][Hdim];        // 4 KB
    __shared__ int nz[2];
    __shared__ int saw[2];

    const int tid = threadIdx.x;
    const int blk = blockIdx.x;

    if (blk >= 256) {
        if (blk < 260) {                     // w1T strips
            const int k0 = (blk - 256) * 32;
            for (int i = tid; i < 32 * 128; i += 1024) {
                int r = i >> 7, c = i & 127;
                w2L[r][c] = w1[(k0 + r) * Hdim + c];
            }
            __syncthreads();
            if (tid < 256) {
                short* o = (short*)(ws + WS_W1T);
                const int n = tid >> 1, j0 = (tid & 1) * 16;
                short tmp[16];
                #pragma unroll
                for (int j = 0; j < 16; ++j) tmp[j] = f2bf(w2L[j0 + j][n]);
                short8* dst = (short8*)(o + n * Hdim + k0 + j0);
                dst[0] = *(short8*)(tmp);
                dst[1] = *(short8*)(tmp + 8);
            }
        } else {                             // init out with bias (overwrites poison)
            if (tid < Bbatch) out[tid] = bfc[0];
        }
        return;
    }

    const int s0 = blk * 2;

    for (int i = tid; i < Anodes; i += 1024) cntL[i] = 0u;
    if (tid < 2) { nz[tid] = 0; saw[tid] = 0; }
    __syncthreads();

    // stage w2 (no dependency on scan), float4
    {
        const float4* w2v = (const float4*)w2;
        for (int i = tid; i < (Hdim * Hdim) / 4; i += 1024) {
            float4 v = w2v[i];
            float* dst = &w2L[i >> 5][(i & 31) * 4];
            dst[0] = v.x; dst[1] = v.y; dst[2] = v.z; dst[3] = v.w;
        }
    }

    // SINGLE shared edge scan: global dst histogram + both sources' dst lists
    const int4* s4 = (const int4*)ei;
    const int4* d4 = (const int4*)(ei + Eedges);
    for (int i = tid; i < Eedges / 4; i += 1024) {   // 4 iterations
        int4 sv = s4[i];
        int4 dv = d4[i];
        int d, ss;
        d = dv.x & AMASK; atomicAdd(&cntL[d], 1u);
        if (d == s0) saw[0] = 1; else if (d == s0 + 1) saw[1] = 1;
        ss = sv.x & AMASK;
        if (ss == s0) dl[0][atomicAdd(&nz[0], 1)] = (unsigned short)d;
        else if (ss == s0 + 1) dl[1][atomicAdd(&nz[1], 1)] = (unsigned short)d;
        d = dv.y & AMASK; atomicAdd(&cntL[d], 1u);
        if (d == s0) saw[0] = 1; else if (d == s0 + 1) saw[1] = 1;
        ss = sv.y & AMASK;
        if (ss == s0) dl[0][atomicAdd(&nz[0], 1)] = (unsigned short)d;
        else if (ss == s0 + 1) dl[1][atomicAdd(&nz[1], 1)] = (unsigned short)d;
        d = dv.z & AMASK; atomicAdd(&cntL[d], 1u);
        if (d == s0) saw[0] = 1; else if (d == s0 + 1) saw[1] = 1;
        ss = sv.z & AMASK;
        if (ss == s0) dl[0][atomicAdd(&nz[0], 1)] = (unsigned short)d;
        else if (ss == s0 + 1) dl[1][atomicAdd(&nz[1], 1)] = (unsigned short)d;
        d = dv.w & AMASK; atomicAdd(&cntL[d], 1u);
        if (d == s0) saw[0] = 1; else if (d == s0 + 1) saw[1] = 1;
        ss = sv.w & AMASK;
        if (ss == s0) dl[0][atomicAdd(&nz[0], 1)] = (unsigned short)d;
        else if (ss == s0 + 1) dl[1][atomicAdd(&nz[1], 1)] = (unsigned short)d;
    }
    __syncthreads();

    const int h  = tid >> 9;        // half: source s0+h
    const int t5 = tid & 511;
    const int n  = nz[h];
    for (int i = t5; i < n; i += 512)
        plist[h][i] = 1.0f / fmaxf((float)cntL[dl[h][i]], 1.0f);
    __syncthreads();

    const int k = tid & 127, q = (tid >> 7) & 3;   // quarter within half
    float g = 0.f;
    for (int i = q; i < n; i += 4)
        g += plist[h][i] * wfc[(size_t)dl[h][i] * Hdim + k];
    qred[h][q][k] = g;
    __syncthreads();
    if (q == 0) Gr[h][k] = qred[h][0][k] + qred[h][1][k] + qred[h][2][k] + qred[h][3][k];
    __syncthreads();

    // U[s0+h,k] = sum_hh w2[k,hh] * Gr[h][hh]  (f32 exact), 4-way split
    float u = 0.f;
    const int h0 = q * 32;
    #pragma unroll 8
    for (int hh = h0; hh < h0 + 32; ++hh) u += w2L[k][hh] * Gr[h][hh];
    qred[h][q][k] = u;
    __syncthreads();
    if (q == 0)
        ws[WS_U + (size_t)(s0 + h) * Hdim + k] =
            qred[h][0][k] + qred[h][1][k] + qred[h][2][k] + qred[h][3][k];

    // c[s0+h] = saw[h] ? b2 . wfc[s0+h,:] : 0
    float cv = 0.f;
    if (t5 < 128) cv = b2[t5] * wfc[(size_t)(s0 + h) * Hdim + t5];
    #pragma unroll
    for (int off = 32; off; off >>= 1) cv += __shfl_down(cv, off, 64);
    __syncthreads();            // qred free for reuse
    if (t5 == 0)  qred[h][0][0] = cv;
    if (t5 == 64) qred[h][0][1] = cv;
    __syncthreads();
    if (t5 == 0) ws[WS_CARR + s0 + h] = saw[h] ? (qred[h][0][0] + qred[h][0][1]) : 0.f;
}

// n2: MFMA; block (b, chunk): partial + chunk-C -> atomicAdd out[b] directly.
__global__ __launch_bounds__(256)
void k_main(const float* __restrict__ x, const float* __restrict__ b1,
            const float* __restrict__ ws, float* __restrict__ out) {
    __shared__ short w1s[Hdim * Hdim];   // swizzled bf16 [n][k], 32 KB
    __shared__ float red[4];

    const int tid  = threadIdx.x;
    const int row0 = blockIdx.x * 64;
    const int b    = blockIdx.x >> 3;
    const int a0   = (blockIdx.x & 7) * 64;

    {
        const short8* gsrc = (const short8*)(ws + WS_W1T);
        for (int i = tid; i < 2048; i += 256) {
            short8 v = gsrc[i];
            int n = i >> 4;
            int byte = (i * 16) ^ ((n & 7) << 4);
            *(short8*)((char*)w1s + byte) = v;
        }
    }
    __syncthreads();

    const int w = tid >> 6;
    const int l = tid & 63;
    const int c = l & 15;
    const int g = l >> 4;

    const float* xrow = x + (size_t)(row0 + w * 16 + c) * Hdim;

    f32x4 acc[8];
    #pragma unroll
    for (int n = 0; n < 8; ++n) acc[n] = (f32x4){0.f, 0.f, 0.f, 0.f};

    #pragma unroll
    for (int ks = 0; ks < 4; ++ks) {
        const int k0 = ks * 32;
        float4 a_lo = *(const float4*)(xrow + k0 + 8 * g);
        float4 a_hi = *(const float4*)(xrow + k0 + 8 * g + 4);
        short8 a;
        a[0] = f2bf(a_lo.x); a[1] = f2bf(a_lo.y); a[2] = f2bf(a_lo.z); a[3] = f2bf(a_lo.w);
        a[4] = f2bf(a_hi.x); a[5] = f2bf(a_hi.y); a[6] = f2bf(a_hi.z); a[7] = f2bf(a_hi.w);
        #pragma unroll
        for (int n = 0; n < 8; ++n) {
            int byte = (((n * 16 + c) << 8) + ((k0 + 8 * g) << 1)) ^ ((c & 7) << 4);
            short8 bf = *(short8*)((char*)w1s + byte);
            acc[n] = __builtin_amdgcn_mfma_f32_16x16x32_bf16(a, bf, acc[n], 0, 0, 0);
        }
    }

    float part = 0.f;
    const float* U = ws + WS_U;
    #pragma unroll
    for (int n = 0; n < 8; ++n) {
        const int colg = n * 16 + c;
        const float bv = b1[colg];
        #pragma unroll
        for (int r = 0; r < 4; ++r) {
            const int arow = a0 + w * 16 + g * 4 + r;
            float z = acc[n][r] + bv;
            part += fmaxf(z, 0.f) * U[arow * Hdim + colg];
        }
    }
    #pragma unroll
    for (int off = 32; off; off >>= 1) part += __shfl_down(part, off, 64);
    if (l == 0) red[w] = part;
    __syncthreads();

    // fold per-chunk C contribution; single atomic per block into out
    float cw = 0.f;
    if (tid < 64) cw = ws[WS_CARR + a0 + tid];
    #pragma unroll
    for (int off = 32; off; off >>= 1) cw += __shfl_down(cw, off, 64);
    if (tid == 0)
        atomicAdd(out + b, red[0] + red[1] + red[2] + red[3] + cw);
}

extern "C" void kernel_launch(void* const* d_in, const int* in_sizes, int n_in,
                              void* d_out, int out_size, void* d_ws, size_t ws_size,
                              hipStream_t stream) {
    const float* x   = (const float*)d_in[0];
    // d_in[1] = pos (unused)
    const int*   ei  = (const int*)d_in[2];
    const float* w1  = (const float*)d_in[3];
    const float* b1  = (const float*)d_in[4];
    const float* w2  = (const float*)d_in[5];
    const float* b2  = (const float*)d_in[6];
    const float* wfc = (const float*)d_in[7];
    const float* bfc = (const float*)d_in[8];
    float* out = (float*)d_out;
    float* ws  = (float*)d_ws;

    hipLaunchKernelGGL(k_G,    dim3(261), dim3(1024), 0, stream,
                       ei, w1, w2, wfc, b2, bfc, ws, out);
    hipLaunchKernelGGL(k_main, dim3(512), dim3(256), 0, stream, x, b1, ws, out);
}